// Round 4
// baseline (595.206 us; speedup 1.0000x reference)
//
#include <hip/hip_runtime.h>

// Problem constants
#define T_TOK 8192
#define HID   2048
#define NH    16
#define NKV   4
#define HD    128

typedef __attribute__((ext_vector_type(8))) short short8;   // 8 x bf16 (4 VGPRs)
typedef __attribute__((ext_vector_type(4))) float f32x4;    // MFMA C/D frag
typedef __attribute__((ext_vector_type(4))) unsigned short us4;

__device__ __forceinline__ unsigned short f2b(float f) {
  union { float f; unsigned int u; } x; x.f = f;
  unsigned int u = x.u;
  return (unsigned short)((u + 0x7FFFu + ((u >> 16) & 1u)) >> 16);
}
__device__ __forceinline__ float b2f(unsigned short u) {
  union { float f; unsigned int u; } x; x.u = ((unsigned int)u) << 16; return x.f;
}

// async global->LDS, 16B per lane; LDS dest is wave-uniform base + lane*16
__device__ __forceinline__ void ld_lds16(const unsigned short* g, unsigned short* l) {
  __builtin_amdgcn_global_load_lds(
      (const __attribute__((address_space(1))) unsigned int*)g,
      (__attribute__((address_space(3))) unsigned int*)l, 16, 0, 0);
}

// ---------------------------------------------------------------------------
// 1) Route scan: perm = [route-0 tokens ... route-1 tokens], plus inverse
// ---------------------------------------------------------------------------
__global__ __launch_bounds__(1024) void scan_route(const int* __restrict__ gm,
                                                   int* __restrict__ perm,
                                                   int* __restrict__ invperm,
                                                   int* __restrict__ n0p) {
  __shared__ int cnt[1024];
  int tid = threadIdx.x;
  int base = tid * 8;
  int r[8]; int c0 = 0;
#pragma unroll
  for (int i = 0; i < 8; i++) { r[i] = gm[base + i] > 0 ? 1 : 0; c0 += 1 - r[i]; }
  cnt[tid] = c0;
  __syncthreads();
  for (int off = 1; off < 1024; off <<= 1) {
    int add = (tid >= off) ? cnt[tid - off] : 0;
    __syncthreads();
    cnt[tid] += add;
    __syncthreads();
  }
  int incl = cnt[tid];
  int total0 = cnt[1023];
  int p0 = incl - c0;
  int p1 = total0 + (base - (incl - c0));
#pragma unroll
  for (int i = 0; i < 8; i++) {
    int t = base + i;
    if (r[i] == 0) { perm[p0] = t; invperm[t] = p0; p0++; }
    else           { perm[p1] = t; invperm[t] = p1; p1++; }
  }
  if (tid == 0) n0p[0] = total0;
}

// ---------------------------------------------------------------------------
// 2) Fused fp32 -> bf16 conversion, ONE launch. Segment 0 (x) is written in
//    PERMUTED row order so the QKV GEMM reads A dense.
// ---------------------------------------------------------------------------
struct ConvArgs {
  const float* src[9];
  unsigned short* dst[9];
  int blk_end[9];   // cumulative 1024-elem block counts
};

__global__ __launch_bounds__(256) void convert_all(ConvArgs a, const int* __restrict__ invperm) {
  int blk = blockIdx.x;
  int s = 0;
  while (blk >= a.blk_end[s]) s++;
  int local = blk - (s ? a.blk_end[s - 1] : 0);
  int i = local * 1024 + threadIdx.x * 4;
  float4 v = *(const float4*)(a.src[s] + i);
  us4 o = { f2b(v.x), f2b(v.y), f2b(v.z), f2b(v.w) };
  if (s == 0) {
    int row = i >> 11, col = i & 2047;          // row is block-uniform
    *(us4*)(a.dst[0] + (size_t)invperm[row] * 2048 + col) = o;
  } else {
    *(us4*)(a.dst[s] + i) = o;
  }
}

// ---------------------------------------------------------------------------
// 3) GEMM core (m97 structure, dense A rows, XOR-swizzled staging).
//    permEpi: nullptr => dense row write; else scatter rows via permEpi.
// ---------------------------------------------------------------------------
#define BM  128
#define BK  64

__device__ __forceinline__ void gemm_core(
    const unsigned short* __restrict__ Xb,
    const unsigned short* __restrict__ W,
    const float* __restrict__ bias,
    const int* __restrict__ permEpi,
    int r0, int r1, int col0, int N,
    float* __restrict__ outF, unsigned short* __restrict__ outB,
    unsigned short* As, unsigned short* Bs)
{
  int tid = threadIdx.x;
  int lane = tid & 63, wid = tid >> 6;
  int quad = lane >> 4, l15 = lane & 15;
  int wr = (wid >> 1) * 64, wc = (wid & 1) * 64;
  int lrow = lane >> 3;
  int sc8 = (lane & 7) ^ (lrow & 7);

  const unsigned short* ag[4]; const unsigned short* bg[4];
  unsigned short* al[4]; unsigned short* bl[4];
#pragma unroll
  for (int i = 0; i < 4; i++) {
    int row = wid * 32 + i * 8 + lrow;
    ag[i] = Xb + (size_t)(r0 + row) * HID + sc8 * 8;   // dense rows
    bg[i] = W + (size_t)(col0 + row) * HID + sc8 * 8;
    al[i] = As + (wid * 32 + i * 8) * BK;
    bl[i] = Bs + (wid * 32 + i * 8) * BK;
  }

  f32x4 zero = {0.f, 0.f, 0.f, 0.f};
  f32x4 acc[4][4];
#pragma unroll
  for (int a = 0; a < 4; a++)
#pragma unroll
    for (int b = 0; b < 4; b++) acc[a][b] = zero;

  for (int k0 = 0; k0 < HID; k0 += BK) {
#pragma unroll
    for (int i = 0; i < 4; i++) {
      ld_lds16(ag[i] + k0, al[i]);
      ld_lds16(bg[i] + k0, bl[i]);
    }
    __syncthreads();
#pragma unroll
    for (int kk = 0; kk < 2; kk++) {
      int cswz = ((kk * 4 + quad) ^ (l15 & 7)) * 8;
      short8 af[4], bf[4];
#pragma unroll
      for (int mt = 0; mt < 4; mt++)
        af[mt] = *(const short8*)&As[(wr + mt * 16 + l15) * BK + cswz];
#pragma unroll
      for (int nt = 0; nt < 4; nt++)
        bf[nt] = *(const short8*)&Bs[(wc + nt * 16 + l15) * BK + cswz];
#pragma unroll
      for (int mt = 0; mt < 4; mt++)
#pragma unroll
        for (int nt = 0; nt < 4; nt++)
          acc[mt][nt] = __builtin_amdgcn_mfma_f32_16x16x32_bf16(af[mt], bf[nt], acc[mt][nt], 0, 0, 0);
    }
    __syncthreads();
  }

#pragma unroll
  for (int mt = 0; mt < 4; mt++) {
#pragma unroll
    for (int r = 0; r < 4; r++) {
      int lr = wr + mt * 16 + quad * 4 + r;
      int gr = r0 + lr;
      if (gr >= r1) continue;
      int tok = permEpi ? permEpi[gr] : gr;
#pragma unroll
      for (int nt = 0; nt < 4; nt++) {
        int col = col0 + wc + nt * 16 + l15;
        float v = acc[mt][nt][r];
        if (bias) v += bias[col];
        if (outF) outF[(size_t)tok * N + col] = v;
        else      outB[(size_t)tok * N + col] = f2b(v);
      }
    }
  }
}

__global__ __launch_bounds__(256, 3) void gemm_qkv(
    const unsigned short* __restrict__ xb,
    const unsigned short* wq0, const unsigned short* wq1,
    const float* bq0, const float* bq1,
    const unsigned short* wk0, const unsigned short* wk1,
    const float* bk0, const float* bk1,
    const unsigned short* wv0, const unsigned short* wv1,
    const float* bv0, const float* bv1,
    unsigned short* qraw, unsigned short* kraw, unsigned short* vb,
    const int* __restrict__ perm, const int* __restrict__ n0p)
{
  __shared__ unsigned short As[BM * BK];
  __shared__ unsigned short Bs[BM * BK];
  int set = blockIdx.z;
  int n0 = n0p[0];
  int r0, r1;
  if (set == 0) { r0 = blockIdx.x * BM; if (r0 >= n0) return; r1 = (r0 + BM < n0) ? r0 + BM : n0; }
  else          { r0 = n0 + blockIdx.x * BM; if (r0 >= T_TOK) return; r1 = (r0 + BM < T_TOK) ? r0 + BM : T_TOK; }
  int y = blockIdx.y;
  const unsigned short* w; const float* bias;
  unsigned short* ob; int col0, N; const int* pe;
  if (y < 16)      { w = set ? wq1 : wq0; bias = set ? bq1 : bq0; col0 = y * 128;        N = HID; ob = qraw; pe = nullptr; }
  else if (y < 20) { w = set ? wk1 : wk0; bias = set ? bk1 : bk0; col0 = (y - 16) * 128; N = 512; ob = kraw; pe = nullptr; }
  else             { w = set ? wv1 : wv0; bias = set ? bv1 : bv0; col0 = (y - 20) * 128; N = 512; ob = vb;   pe = perm; }
  gemm_core(xb, w, bias, pe, r0, r1, col0, N, nullptr, ob, As, Bs);
}

__global__ __launch_bounds__(256, 3) void gemm_out(
    const unsigned short* __restrict__ obuf,
    const unsigned short* wo0, const unsigned short* wo1,
    float* __restrict__ out,
    const int* __restrict__ perm, const int* __restrict__ n0p)
{
  __shared__ unsigned short As[BM * BK];
  __shared__ unsigned short Bs[BM * BK];
  int set = blockIdx.z;
  int n0 = n0p[0];
  int r0, r1;
  if (set == 0) { r0 = blockIdx.x * BM; if (r0 >= n0) return; r1 = (r0 + BM < n0) ? r0 + BM : n0; }
  else          { r0 = n0 + blockIdx.x * BM; if (r0 >= T_TOK) return; r1 = (r0 + BM < T_TOK) ? r0 + BM : T_TOK; }
  gemm_core(obuf, set ? wo1 : wo0, nullptr, perm, r0, r1, blockIdx.y * 128, HID, out, nullptr, As, Bs);
}

// ---------------------------------------------------------------------------
// 4) Fused RMSNorm + RoPE for q AND k in one launch. Input rows are in
//    permuted order (dense GEMM output); output scattered to token order.
// ---------------------------------------------------------------------------
__global__ __launch_bounds__(256) void rms_rope_all(
    const unsigned short* __restrict__ qraw, const unsigned short* __restrict__ kraw,
    unsigned short* __restrict__ qbuf, unsigned short* __restrict__ kbuf,
    const float* __restrict__ cosb, const float* __restrict__ sinb,
    const int* __restrict__ perm, const int* __restrict__ gm,
    const float* __restrict__ qnw, const float* __restrict__ qngw,
    const float* __restrict__ knw, const float* __restrict__ kngw)
{
  int wvid = blockIdx.x * 4 + (threadIdx.x >> 6);
  int lane = threadIdx.x & 63;
  const unsigned short* in; unsigned short* outp;
  const float *wn, *wg;
  int t;
  if (wvid < T_TOK * NH) {
    int r = wvid >> 4, h = wvid & 15;
    t = perm[r];
    in = qraw + ((size_t)r * NH + h) * HD;
    outp = qbuf + ((size_t)t * NH + h) * HD;
    wn = qnw; wg = qngw;
  } else {
    int w2 = wvid - T_TOK * NH;
    int r = w2 >> 2, h = w2 & 3;
    t = perm[r];
    in = kraw + ((size_t)r * NKV + h) * HD;
    outp = kbuf + ((size_t)t * NKV + h) * HD;
    wn = knw; wg = kngw;
  }
  float x1 = b2f(in[lane]), x2 = b2f(in[64 + lane]);
  float ss = x1 * x1 + x2 * x2;
#pragma unroll
  for (int o = 32; o > 0; o >>= 1) ss += __shfl_xor(ss, o, 64);
  float inv = rsqrtf(ss * (1.0f / 128.0f) + 1e-6f);
  const float* w = (gm[t] > 0) ? wg : wn;
  float n1 = x1 * inv * w[lane];
  float n2 = x2 * inv * w[lane + 64];
  float c1 = cosb[t * HD + lane],      s1 = sinb[t * HD + lane];
  float c2 = cosb[t * HD + 64 + lane], s2 = sinb[t * HD + 64 + lane];
  outp[lane]      = f2b(n1 * c1 - n2 * s1);
  outp[64 + lane] = f2b(n2 * c2 + n1 * s2);
}

// ---------------------------------------------------------------------------
// 4b) V transpose: vb[tok][kvh][d] (token order) -> vt[b][kvh][d][1024]
// ---------------------------------------------------------------------------
__global__ __launch_bounds__(256) void vtrans(const unsigned short* __restrict__ vb,
                                              unsigned short* __restrict__ vt) {
  __shared__ unsigned short Vs[64][136];
  int kt = blockIdx.x, kvh = blockIdx.y, b = blockIdx.z;
  int t = threadIdx.x;
  int kv0 = kt * 64;
  int key = t >> 2, c0 = t & 3;
#pragma unroll
  for (int i = 0; i < 4; i++) {
    int cc = c0 * 4 + i;
    *(short8*)&Vs[key][cc * 8] =
        *(const short8*)(vb + ((size_t)(b * 1024 + kv0 + key) * NKV + kvh) * HD + cc * 8);
  }
  __syncthreads();
  int d = t >> 1, hh = t & 1;
  unsigned short tmp[32];
#pragma unroll
  for (int k = 0; k < 32; k++) tmp[k] = Vs[hh * 32 + k][d];
  size_t base = ((size_t)(b * NKV + kvh) * HD + d) * 1024 + kv0 + hh * 32;
  *(short8*)(vt + base)      = *(short8*)&tmp[0];
  *(short8*)(vt + base + 8)  = *(short8*)&tmp[8];
  *(short8*)(vt + base + 16) = *(short8*)&tmp[16];
  *(short8*)(vt + base + 24) = *(short8*)&tmp[24];
}

// ---------------------------------------------------------------------------
// 5) Flash attention v4: 4 waves = 4 heads of one kvh group; each wave owns
//    32 q rows (2 q16 groups) so every Ks/Vt fragment read feeds 2 MFMAs.
//    K and V staged via global_load_lds with XOR chunk swizzle. Pair-slot
//    causal balancing ({p, 31-p} -> 17 k-tiles/block). Static-max softmax.
//    Output written in PERMUTED row order (dense A for gemm_out).
// ---------------------------------------------------------------------------
__global__ __launch_bounds__(256, 2) void attn_kernel(
    const unsigned short* __restrict__ qb,
    const unsigned short* __restrict__ kb,
    const unsigned short* __restrict__ vt,
    const int* __restrict__ invperm,
    unsigned short* __restrict__ ob)
{
  __shared__ unsigned short Ks[64 * 128];    // [key][d], chunk-swizzled
  __shared__ unsigned short Vt[128 * 64];    // [d][key], chunk-swizzled
  __shared__ unsigned short Ps[4 * 32 * 64]; // per-wave P [32 qrow][64 key]
  int pslot = blockIdx.x, kvh = blockIdx.y, b = blockIdx.z;
  int tid = threadIdx.x, lane = tid & 63, wid = tid >> 6;
  int quad = lane >> 4, l15 = lane & 15;
  int h = kvh * 4 + wid;
  const float sc = 0.088388347648318447f;    // 1/sqrt(128)
  f32x4 zero = {0.f, 0.f, 0.f, 0.f};

  // staging geometry (wave-uniform LDS bases, XOR swizzle on global chunk)
  int skey = (wid << 2) + (lane >> 4);           // K row, + i*16
  int kswz = ((lane & 15) ^ (skey & 7)) * 8;
  int sd   = (wid << 3) + (lane >> 3);           // V row, + i*32
  int vswz = ((lane & 7) ^ (sd & 7)) * 8;

  for (int half = 0; half < 2; half++) {
    int a = half ? (31 - pslot) : pslot;         // q32-tile index 0..31
    int q0 = a * 32;
    short8 qfr[2][4];
#pragma unroll
    for (int g = 0; g < 2; g++) {
      size_t qoff = ((size_t)(b * 1024 + q0 + g * 16 + l15) * NH + h) * HD;
#pragma unroll
      for (int kk = 0; kk < 4; kk++)
        qfr[g][kk] = *(const short8*)(qb + qoff + kk * 32 + quad * 8);
    }
    f32x4 oacc[2][8];
#pragma unroll
    for (int g = 0; g < 2; g++)
#pragma unroll
      for (int i = 0; i < 8; i++) oacc[g][i] = zero;
    float lp[2][4] = {{0.f,0.f,0.f,0.f},{0.f,0.f,0.f,0.f}};

    int ktiles = a / 2 + 1;
    for (int kt = 0; kt < ktiles; kt++) {
      int kv0 = kt * 64;
      __syncthreads();   // guard LDS reuse
#pragma unroll
      for (int i = 0; i < 4; i++)   // K: 64 keys x 256B
        ld_lds16(kb + ((size_t)(b * 1024 + kv0 + i * 16 + skey) * NKV + kvh) * HD + kswz,
                 Ks + (size_t)(i * 16 + (wid << 2)) * 128);
#pragma unroll
      for (int i = 0; i < 4; i++)   // V: 128 d-rows x 128B
        ld_lds16(vt + ((size_t)(b * NKV + kvh) * HD + (i * 32 + sd)) * 1024 + kv0 + vswz,
                 Vt + (size_t)(i * 32 + (wid << 3)) * 64);
      __syncthreads();
      bool lastt = (kt == ktiles - 1);

      // S = Q K^T : each bfr feeds both q16 groups
      f32x4 s[2][4];
#pragma unroll
      for (int g4 = 0; g4 < 4; g4++) {
        short8 bfr[4];
#pragma unroll
        for (int kk = 0; kk < 4; kk++)
          bfr[kk] = *(const short8*)&Ks[(g4 * 16 + l15) * 128 + ((kk * 4 + quad) ^ (l15 & 7)) * 8];
#pragma unroll
        for (int g = 0; g < 2; g++) {
          f32x4 acc = zero;
#pragma unroll
          for (int kk = 0; kk < 4; kk++)
            acc = __builtin_amdgcn_mfma_f32_16x16x32_bf16(qfr[g][kk], bfr[kk], acc, 0, 0, 0);
          s[g][g4] = acc;
        }
      }
      // softmax (static max) + P store into per-wave LDS region
#pragma unroll
      for (int g = 0; g < 2; g++) {
#pragma unroll
        for (int g4 = 0; g4 < 4; g4++) {
          int col = kv0 + g4 * 16 + l15;
          int k8 = g4 * 2 + (l15 >> 3);
#pragma unroll
          for (int r = 0; r < 4; r++) {
            float p = __expf(s[g][g4][r] * sc);
            int row = q0 + g * 16 + quad * 4 + r;
            if (lastt && col > row) p = 0.f;
            lp[g][r] += p;
            int rloc = g * 16 + quad * 4 + r;
            Ps[wid * 2048 + rloc * 64 + ((k8 ^ (rloc & 7)) * 8 + (l15 & 7))] = f2b(p);
          }
        }
      }
      // O += P V : each vf feeds both q16 groups
#pragma unroll
      for (int kk = 0; kk < 2; kk++) {
        short8 pa[2];
#pragma unroll
        for (int g = 0; g < 2; g++)
          pa[g] = *(const short8*)&Ps[wid * 2048 + (g * 16 + l15) * 64 + ((kk * 4 + quad) ^ (l15 & 7)) * 8];
#pragma unroll
        for (int dg = 0; dg < 8; dg++) {
          short8 vf = *(const short8*)&Vt[(dg * 16 + l15) * 64 + ((kk * 4 + quad) ^ (l15 & 7)) * 8];
#pragma unroll
          for (int g = 0; g < 2; g++)
            oacc[g][dg] = __builtin_amdgcn_mfma_f32_16x16x32_bf16(pa[g], vf, oacc[g][dg], 0, 0, 0);
        }
      }
    }
    // finalize: deferred l-reduction + permuted store
#pragma unroll
    for (int g = 0; g < 2; g++) {
#pragma unroll
      for (int r = 0; r < 4; r++) {
        float v = lp[g][r];
#pragma unroll
        for (int o = 8; o > 0; o >>= 1) v += __shfl_xor(v, o, 64);
        lp[g][r] = 1.0f / v;
      }
#pragma unroll
      for (int r = 0; r < 4; r++) {
        int row = q0 + g * 16 + quad * 4 + r;
        int prow = invperm[b * 1024 + row];
#pragma unroll
        for (int dg = 0; dg < 8; dg++)
          ob[(size_t)prow * HID + h * 128 + dg * 16 + l15] = f2b(oacc[g][dg][r] * lp[g][r]);
      }
    }
  }
}

// ---------------------------------------------------------------------------
extern "C" void kernel_launch(void* const* d_in, const int* in_sizes, int n_in,
                              void* d_out, int out_size, void* d_ws, size_t ws_size,
                              hipStream_t stream) {
  const float* x    = (const float*)d_in[0];
  const float* cosb = (const float*)d_in[1];
  const float* sinb = (const float*)d_in[2];
  // d_in[3] attn_bias: exactly causal -> applied implicitly
  const int*   gm   = (const int*)d_in[4];
  const float* Wq   = (const float*)d_in[5];
  const float* bq   = (const float*)d_in[6];
  const float* Wqg  = (const float*)d_in[7];
  const float* bqg  = (const float*)d_in[8];
  const float* Wk   = (const float*)d_in[9];
  const float* bk   = (const float*)d_in[10];
  const float* Wkg  = (const float*)d_in[11];
  const float* bkg  = (const float*)d_in[12];
  const float* Wv   = (const float*)d_in[13];
  const float* bv   = (const float*)d_in[14];
  const float* Wvg  = (const float*)d_in[15];
  const float* bvg  = (const float*)d_in[16];
  const float* Wo   = (const float*)d_in[17];
  const float* Wog  = (const float*)d_in[18];
  const float* qnw  = (const float*)d_in[19];
  const float* qngw = (const float*)d_in[20];
  const float* knw  = (const float*)d_in[21];
  const float* kngw = (const float*)d_in[22];
  float* out = (float*)d_out;

  char* wsb = (char*)d_ws;
  size_t off = 0;
  auto alloc = [&](size_t bytes) -> char* {
    char* p = wsb + off;
    off += (bytes + 255) & ~(size_t)255;
    return p;
  };
  int* perm    = (int*)alloc((size_t)T_TOK * 4);
  int* invperm = (int*)alloc((size_t)T_TOK * 4);
  int* n0p     = (int*)alloc(4);
  unsigned short* xb  = (unsigned short*)alloc((size_t)T_TOK * HID * 2);
  unsigned short* wq0 = (unsigned short*)alloc((size_t)HID * HID * 2);
  unsigned short* wq1 = (unsigned short*)alloc((size_t)HID * HID * 2);
  unsigned short* wk0 = (unsigned short*)alloc((size_t)512 * HID * 2);
  unsigned short* wk1 = (unsigned short*)alloc((size_t)512 * HID * 2);
  unsigned short* wv0 = (unsigned short*)alloc((size_t)512 * HID * 2);
  unsigned short* wv1 = (unsigned short*)alloc((size_t)512 * HID * 2);
  unsigned short* wo0 = (unsigned short*)alloc((size_t)HID * HID * 2);
  unsigned short* wo1 = (unsigned short*)alloc((size_t)HID * HID * 2);
  unsigned short* qraw = (unsigned short*)alloc((size_t)T_TOK * HID * 2);
  unsigned short* kraw = (unsigned short*)alloc((size_t)T_TOK * 512 * 2);
  unsigned short* vbuf = (unsigned short*)alloc((size_t)T_TOK * 512 * 2);
  unsigned short* vtb  = (unsigned short*)alloc((size_t)T_TOK * 512 * 2);
  unsigned short* qbuf = (unsigned short*)alloc((size_t)T_TOK * HID * 2);
  unsigned short* kbuf = (unsigned short*)alloc((size_t)T_TOK * 512 * 2);
  unsigned short* obuf = qraw;   // qraw dead after rms_rope; alias

  scan_route<<<dim3(1), dim3(1024), 0, stream>>>(gm, perm, invperm, n0p);

  ConvArgs ca;
  const float* srcs[9] = {x, Wq, Wqg, Wk, Wkg, Wv, Wvg, Wo, Wog};
  unsigned short* dsts[9] = {xb, wq0, wq1, wk0, wk1, wv0, wv1, wo0, wo1};
  int ns[9] = {T_TOK * HID, HID * HID, HID * HID, 512 * HID, 512 * HID,
               512 * HID, 512 * HID, HID * HID, HID * HID};
  int cum = 0;
  for (int i = 0; i < 9; i++) {
    ca.src[i] = srcs[i]; ca.dst[i] = dsts[i];
    cum += ns[i] / 1024; ca.blk_end[i] = cum;
  }
  convert_all<<<dim3(cum), dim3(256), 0, stream>>>(ca, invperm);

  gemm_qkv<<<dim3(64, 24, 2), dim3(256), 0, stream>>>(
      xb, wq0, wq1, bq, bqg, wk0, wk1, bk, bkg, wv0, wv1, bv, bvg,
      qraw, kraw, vbuf, perm, n0p);

  rms_rope_all<<<dim3((T_TOK * (NH + NKV)) / 4), dim3(256), 0, stream>>>(
      qraw, kraw, qbuf, kbuf, cosb, sinb, perm, gm, qnw, qngw, knw, kngw);
  vtrans<<<dim3(16, 4, 8), dim3(256), 0, stream>>>(vbuf, vtb);

  attn_kernel<<<dim3(16, 4, 8), dim3(256), 0, stream>>>(qbuf, kbuf, vtb, invperm, obuf);

  gemm_out<<<dim3(64, 16, 2), dim3(256), 0, stream>>>(obuf, wo0, wo1, out, perm, n0p);
}